// Round 1
// baseline (263.974 us; speedup 1.0000x reference)
//
#include <hip/hip_runtime.h>
#include <stdint.h>

// Problem constants
#define BATCH 16384
#define INDIM 256
#define DDIM  128
#define NEXP  8

typedef __bf16 bfv8  __attribute__((ext_vector_type(8)));   // MFMA A/B frag: 8 bf16 = 4 VGPRs
typedef float  f32x4 __attribute__((ext_vector_type(4)));   // MFMA C/D frag

// ---------------------------------------------------------------------------
// Prep kernel: repack Wa/Wb/Ws (fp32 [8,256,128]) and Gcat (Ga16|Gb16|Gs24 pad
// to 64 rows) into bf16 MFMA B-fragment layout so the main kernel's B loads
// are contiguous 1KB-per-wave dwordx4.
//   W frag slot t = (((st*8+e)*8+kt)*8+nt)*64+lane ; elem j = W[i][d] with
//     i = kt*32 + (lane>>4)*8 + j,  d = nt*16 + (lane&15)
//   G frag slot t2 = (kt*4+nt)*64+lane ; row g = nt*16+(lane&15), col k likewise
// ---------------------------------------------------------------------------
__global__ void prep_kernel(const float* __restrict__ Wa, const float* __restrict__ Wb,
                            const float* __restrict__ Ws, const float* __restrict__ Ga,
                            const float* __restrict__ Gb, const float* __restrict__ Gs,
                            __bf16* __restrict__ wp, __bf16* __restrict__ gp) {
    int t = blockIdx.x * 256 + threadIdx.x;
    const int NW = 3 * 8 * 8 * 8 * 64;   // 98304 W-frag slots
    if (t < NW) {
        int lane = t & 63, nt = (t >> 6) & 7, kt = (t >> 9) & 7, e = (t >> 12) & 7, st = t >> 15;
        const float* W = (st == 0) ? Wa : (st == 1) ? Wb : Ws;
        int d  = nt * 16 + (lane & 15);
        int i0 = kt * 32 + (lane >> 4) * 8;
        __bf16* o = wp + (size_t)t * 8;
#pragma unroll
        for (int j = 0; j < 8; j++)
            o[j] = (__bf16)W[(size_t)(e * 256 + i0 + j) * 128 + d];
    } else if (t < NW + 2048) {
        int t2 = t - NW;
        int lane = t2 & 63, nt = (t2 >> 6) & 3, kt = t2 >> 8;
        int g  = nt * 16 + (lane & 15);
        int k0 = kt * 32 + (lane >> 4) * 8;
        __bf16* o = gp + (size_t)t2 * 8;
#pragma unroll
        for (int j = 0; j < 8; j++) {
            int k = k0 + j;
            float v = 0.f;
            if (g < 16)      v = Ga[g * 256 + k];
            else if (g < 32) v = Gb[(g - 16) * 256 + k];
            else if (g < 56) v = Gs[(g - 32) * 256 + k];
            o[j] = (__bf16)v;
        }
    }
}

// ---------------------------------------------------------------------------
// Main fused kernel. Grid 256 blocks (1/CU) x 256 threads (4 waves).
// Block owns 64 batch rows. Wave w owns output cols [32w, 32w+32).
// Phase 1: logits via MFMA (wave s computes stream s's gates), softmax -> LDS
//          transposed weight table wT[gate][row].
// Phase 2: per stream, per expert: 64x128 bf16 MFMA tile from registers(A) x
//          L2-direct B frags; add bias; fold into 3 output accumulators with
//          per-row gate weights (ds_read_b128 of 4 consecutive rows).
// ---------------------------------------------------------------------------
__launch_bounds__(256, 1)
__global__ void ple_kernel(const float* __restrict__ xa, const float* __restrict__ xb,
                           const float* __restrict__ xs,
                           const float* __restrict__ ba, const float* __restrict__ bb,
                           const float* __restrict__ bs,
                           const __bf16* __restrict__ wp, const __bf16* __restrict__ gp,
                           float* __restrict__ out) {
    __shared__ float lgt[64 * 64];   // logits [row][gate]
    __shared__ float wT[64 * 64];    // softmax weights transposed [gate][row]

    const int tid  = threadIdx.x;
    const int w    = tid >> 6;       // wave id 0..3
    const int lane = tid & 63;
    const int quad = lane >> 4;      // 0..3
    const int l16  = lane & 15;
    const int r0   = blockIdx.x * 64;

    const float* xptr[3] = {xa, xb, xs};
    const float* bptr[3] = {ba, bb, bs};

    bfv8 afr[4][8];                  // A frags: 4 row-tiles x 8 k-tiles (128 VGPRs)

    // ---------------- Phase 1: gate logits via MFMA ----------------
    if (w < 3) {
        const float* x = xptr[w];
#pragma unroll
        for (int mt = 0; mt < 4; mt++) {
            const float* xr = x + (size_t)(r0 + mt * 16 + l16) * INDIM;
#pragma unroll
            for (int kt = 0; kt < 8; kt++) {
                f32x4 lo = *(const f32x4*)(xr + kt * 32 + quad * 8);
                f32x4 hi = *(const f32x4*)(xr + kt * 32 + quad * 8 + 4);
                bfv8 a;
                a[0] = (__bf16)lo[0]; a[1] = (__bf16)lo[1]; a[2] = (__bf16)lo[2]; a[3] = (__bf16)lo[3];
                a[4] = (__bf16)hi[0]; a[5] = (__bf16)hi[1]; a[6] = (__bf16)hi[2]; a[7] = (__bf16)hi[3];
                afr[mt][kt] = a;
            }
        }
        const int nt0 = (w == 2) ? 2 : w;    // wave0->Ga(nt0), wave1->Gb(nt1), wave2->Gs(nt2,3)
        const int nnt = (w == 2) ? 2 : 1;
        for (int ntl = 0; ntl < nnt; ntl++) {
            int nt = nt0 + ntl;
            f32x4 acc[4];
#pragma unroll
            for (int mt = 0; mt < 4; mt++) { f32x4 z = {0.f, 0.f, 0.f, 0.f}; acc[mt] = z; }
#pragma unroll
            for (int kt = 0; kt < 8; kt++) {
                bfv8 g = *(const bfv8*)(gp + ((size_t)(kt * 4 + nt) * 64 + lane) * 8);
#pragma unroll
                for (int mt = 0; mt < 4; mt++)
                    acc[mt] = __builtin_amdgcn_mfma_f32_16x16x32_bf16(afr[mt][kt], g, acc[mt], 0, 0, 0);
            }
#pragma unroll
            for (int mt = 0; mt < 4; mt++)
#pragma unroll
                for (int r = 0; r < 4; r++)
                    lgt[(mt * 16 + quad * 4 + r) * 64 + nt * 16 + l16] = acc[mt][r];
        }
    }
    __syncthreads();

    // ---------------- softmax per row, 3 gate groups; store transposed ----------------
    if (tid < 64) {
        const float* L = lgt + tid * 64;
#pragma unroll
        for (int gi = 0; gi < 3; gi++) {
            const int base = (gi == 0) ? 0 : (gi == 1 ? 16 : 32);
            const int cnt  = (gi == 2) ? 24 : 16;
            float m = -1e30f;
            for (int k = 0; k < cnt; k++) m = fmaxf(m, L[base + k]);
            float s = 0.f;
            for (int k = 0; k < cnt; k++) s += __expf(L[base + k] - m);
            float inv = 1.f / s;
            for (int k = 0; k < cnt; k++) wT[(base + k) * 64 + tid] = __expf(L[base + k] - m) * inv;
        }
    }
    __syncthreads();

    // ---------------- Phase 2: experts + gated accumulation ----------------
    float o[3][4][2][4];             // [out][mt][ntl][reg] = 96 VGPRs
#pragma unroll
    for (int oi = 0; oi < 3; oi++)
#pragma unroll
        for (int mt = 0; mt < 4; mt++)
#pragma unroll
            for (int ntl = 0; ntl < 2; ntl++)
#pragma unroll
                for (int r = 0; r < 4; r++) o[oi][mt][ntl][r] = 0.f;

// fold expert tile (acc, already biased) into output oi with gate column gbase+e
#define FOLD(oi, gbase)                                                          \
    {                                                                            \
        _Pragma("unroll")                                                        \
        for (int mt = 0; mt < 4; mt++) {                                         \
            f32x4 wv = *(const f32x4*)(wT + (gbase + e) * 64 + mt * 16 + quad * 4); \
            _Pragma("unroll")                                                    \
            for (int ntl = 0; ntl < 2; ntl++)                                    \
                _Pragma("unroll")                                                \
                for (int r = 0; r < 4; r++)                                      \
                    o[oi][mt][ntl][r] += wv[r] * acc[mt][ntl][r];                \
        }                                                                        \
    }

#pragma unroll
    for (int st = 0; st < 3; st++) {
        const float* x = xptr[st];
#pragma unroll
        for (int mt = 0; mt < 4; mt++) {
            const float* xr = x + (size_t)(r0 + mt * 16 + l16) * INDIM;
#pragma unroll
            for (int kt = 0; kt < 8; kt++) {
                f32x4 lo = *(const f32x4*)(xr + kt * 32 + quad * 8);
                f32x4 hi = *(const f32x4*)(xr + kt * 32 + quad * 8 + 4);
                bfv8 a;
                a[0] = (__bf16)lo[0]; a[1] = (__bf16)lo[1]; a[2] = (__bf16)lo[2]; a[3] = (__bf16)lo[3];
                a[4] = (__bf16)hi[0]; a[5] = (__bf16)hi[1]; a[6] = (__bf16)hi[2]; a[7] = (__bf16)hi[3];
                afr[mt][kt] = a;
            }
        }
        const float* bias = bptr[st];
#pragma unroll
        for (int e = 0; e < NEXP; e++) {
            // B frags for this expert, this wave's 2 n-tiles: 16x coalesced 1KB loads (L2)
            bfv8 bf[8][2];
#pragma unroll
            for (int kt = 0; kt < 8; kt++)
#pragma unroll
                for (int ntl = 0; ntl < 2; ntl++)
                    bf[kt][ntl] = *(const bfv8*)(wp +
                        ((size_t)(((st * 8 + e) * 8 + kt) * 8 + (2 * w + ntl)) * 64 + lane) * 8);

            f32x4 acc[4][2];
#pragma unroll
            for (int mt = 0; mt < 4; mt++)
#pragma unroll
                for (int ntl = 0; ntl < 2; ntl++) { f32x4 z = {0.f, 0.f, 0.f, 0.f}; acc[mt][ntl] = z; }

#pragma unroll
            for (int kt = 0; kt < 8; kt++)
#pragma unroll
                for (int ntl = 0; ntl < 2; ntl++)
#pragma unroll
                    for (int mt = 0; mt < 4; mt++)
                        acc[mt][ntl] = __builtin_amdgcn_mfma_f32_16x16x32_bf16(
                            afr[mt][kt], bf[kt][ntl], acc[mt][ntl], 0, 0, 0);

            // bias (per output column)
            float b0 = bias[e * 128 + w * 32 + l16];
            float b1 = bias[e * 128 + w * 32 + 16 + l16];
#pragma unroll
            for (int mt = 0; mt < 4; mt++)
#pragma unroll
                for (int r = 0; r < 4; r++) { acc[mt][0][r] += b0; acc[mt][1][r] += b1; }

            // gated fold. Gate table columns: a:0-15, b:16-31, s:32-55.
            // out_a = cat(ea,es): ea->g=e,   es->g=8+e
            // out_b = cat(eb,es): eb->g=16+e (local 0..7), es->g=24+e
            // out_s = cat(ea,eb,es): ea->32+e, eb->40+e, es->48+e
            if (st == 0)      { FOLD(0, 0);  FOLD(2, 32); }
            else if (st == 1) { FOLD(1, 16); FOLD(2, 40); }
            else              { FOLD(0, 8);  FOLD(1, 24); FOLD(2, 48); }
        }
    }
#undef FOLD

    // ---------------- epilogue: store 3 outputs ----------------
#pragma unroll
    for (int oi = 0; oi < 3; oi++) {
        float* ob = out + (size_t)oi * BATCH * DDIM;
#pragma unroll
        for (int mt = 0; mt < 4; mt++)
#pragma unroll
            for (int r = 0; r < 4; r++) {
                int row = r0 + mt * 16 + quad * 4 + r;
#pragma unroll
                for (int ntl = 0; ntl < 2; ntl++)
                    ob[(size_t)row * DDIM + w * 32 + ntl * 16 + l16] = o[oi][mt][ntl][r];
            }
    }
}

extern "C" void kernel_launch(void* const* d_in, const int* in_sizes, int n_in,
                              void* d_out, int out_size, void* d_ws, size_t ws_size,
                              hipStream_t stream) {
    const float* xa = (const float*)d_in[0];
    const float* xb = (const float*)d_in[1];
    const float* xs = (const float*)d_in[2];
    const float* Wa = (const float*)d_in[3];
    const float* ba = (const float*)d_in[4];
    const float* Wb = (const float*)d_in[5];
    const float* bb = (const float*)d_in[6];
    const float* Ws = (const float*)d_in[7];
    const float* bs = (const float*)d_in[8];
    const float* Ga = (const float*)d_in[9];
    const float* Gb = (const float*)d_in[10];
    const float* Gs = (const float*)d_in[11];

    __bf16* wp = (__bf16*)d_ws;            // 786432 bf16 = 1.5 MB packed expert weights
    __bf16* gp = wp + 3 * 8 * 8 * 8 * 64 * 8;  // 16384 bf16 packed gate matrix

    prep_kernel<<<392, 256, 0, stream>>>(Wa, Wb, Ws, Ga, Gb, Gs, wp, gp);
    ple_kernel<<<256, 256, 0, stream>>>(xa, xb, xs, ba, bb, bs, wp, gp, (float*)d_out);
}